// Round 11
// baseline (501.522 us; speedup 1.0000x reference)
//
#include <hip/hip_runtime.h>
#include <hip/hip_fp16.h>
#include <math.h>

#define CDIV(a, b) (((a) + (b) - 1) / (b))
#define SCAN_BS 1024

// ---------- float <-> monotone-unsigned encoding for atomicMax on floats ----
__device__ __forceinline__ unsigned encf(float v) {
    unsigned u = __float_as_uint(v);
    return (u & 0x80000000u) ? ~u : (u | 0x80000000u);
}
__device__ __forceinline__ float decf(unsigned k) {
    unsigned u = (k & 0x80000000u) ? (k ^ 0x80000000u) : ~k;
    return __uint_as_float(u);
}

__device__ __forceinline__ float lrelu(float v) {
    return v > 0.f ? v : 0.2f * v;
}

// ---------- typed 4-element store (fp32 or fp16 output) ---------------------
template <typename OT>
__device__ __forceinline__ void store4(OT* p, const float* a);
template <>
__device__ __forceinline__ void store4<float>(float* p, const float* a) {
    *(float4*)p = *(const float4*)a;
}
template <>
__device__ __forceinline__ void store4<__half>(__half* p, const float* a) {
    __half2 p0 = __floats2half2_rn(a[0], a[1]);
    __half2 p1 = __floats2half2_rn(a[2], a[3]);
    uint2 u;
    u.x = *(unsigned*)&p0;
    u.y = *(unsigned*)&p1;
    *(uint2*)p = u;
}

// ---------- naive GEMM fallback (only if shapes are unexpected) -------------
__global__ __launch_bounds__(256) void gemm_kernel(
    const float* __restrict__ X, const float* __restrict__ W,
    float* __restrict__ Y, int M, int K, int Nout) {
    int idx = blockIdx.x * blockDim.x + threadIdx.x;
    if (idx >= M * Nout) return;
    int row = idx / Nout;
    int col = idx - row * Nout;
    const float* xr = X + (size_t)row * K;
    const float* wc = W + col;
    float acc = 0.f;
    for (int k = 0; k < K; k += 4) {
        float4 xv = *(const float4*)(xr + k);
        acc += xv.x * wc[(size_t)(k + 0) * Nout];
        acc += xv.y * wc[(size_t)(k + 1) * Nout];
        acc += xv.z * wc[(size_t)(k + 2) * Nout];
        acc += xv.w * wc[(size_t)(k + 3) * Nout];
    }
    Y[idx] = acc;
}

// ---------- LDS-tiled GEMM + fused attention dot-products -------------------
template <int K, int NOUT, int RPT, int H, typename OT>
__global__ __launch_bounds__(256) void gemm_attn(
    const float* __restrict__ X, const float* __restrict__ W,
    const float* __restrict__ asrc, const float* __restrict__ adst,
    OT* __restrict__ Y, float* __restrict__ es, float* __restrict__ ed,
    int M) {
    constexpr int TX = NOUT / 4;
    constexpr int TY = 256 / TX;
    constexpr int ROWS = TY * RPT;
    constexpr int KB = (K > 64) ? 64 : K;
    constexpr int C = 32;       // head dim
    constexpr int GP = C / 4;   // 8 threads per (row, head)
    __shared__ float Wl[KB * NOUT];
    const int t = threadIdx.x;
    const int tx = t % TX;
    const int ty = t / TX;
    const int row0 = blockIdx.x * ROWS + ty;
    const float* xp[RPT];
#pragma unroll
    for (int i = 0; i < RPT; ++i) {
        int r = row0 + TY * i;
        xp[i] = X + (size_t)(r < M ? r : (M - 1)) * K;
    }
    float acc[RPT][4] = {};
    for (int kb = 0; kb < K; kb += KB) {
        constexpr int NLD = KB * NOUT / 4 / 256;
        const float4* wg = (const float4*)(W + (size_t)kb * NOUT);
#pragma unroll
        for (int j = 0; j < NLD; ++j) {
            int idx = t + 256 * j;
            ((float4*)Wl)[idx] = wg[idx];
        }
        __syncthreads();
#pragma unroll 2
        for (int k4 = 0; k4 < KB / 4; ++k4) {
            float4 xv[RPT];
#pragma unroll
            for (int i = 0; i < RPT; ++i)
                xv[i] = *(const float4*)(xp[i] + kb + 4 * k4);
            float4 wv[4];
#pragma unroll
            for (int j = 0; j < 4; ++j)
                wv[j] = *(const float4*)&Wl[(4 * k4 + j) * NOUT + tx * 4];
#pragma unroll
            for (int i = 0; i < RPT; ++i) {
                acc[i][0] += xv[i].x * wv[0].x + xv[i].y * wv[1].x +
                             xv[i].z * wv[2].x + xv[i].w * wv[3].x;
                acc[i][1] += xv[i].x * wv[0].y + xv[i].y * wv[1].y +
                             xv[i].z * wv[2].y + xv[i].w * wv[3].y;
                acc[i][2] += xv[i].x * wv[0].z + xv[i].y * wv[1].z +
                             xv[i].z * wv[2].z + xv[i].w * wv[3].z;
                acc[i][3] += xv[i].x * wv[0].w + xv[i].y * wv[1].w +
                             xv[i].z * wv[2].w + xv[i].w * wv[3].w;
            }
        }
        __syncthreads();
    }
    const int hh = tx / GP;      // head of this thread's 4 cols
    const int q = tx % GP;       // position within head
    float asv[4], adv[4];
#pragma unroll
    for (int j = 0; j < 4; ++j) {
        asv[j] = asrc[hh * C + q * 4 + j];
        adv[j] = adst[hh * C + q * 4 + j];
    }
#pragma unroll
    for (int i = 0; i < RPT; ++i) {
        int r = row0 + TY * i;
        float ps = acc[i][0] * asv[0] + acc[i][1] * asv[1] +
                   acc[i][2] * asv[2] + acc[i][3] * asv[3];
        float pd = acc[i][0] * adv[0] + acc[i][1] * adv[1] +
                   acc[i][2] * adv[2] + acc[i][3] * adv[3];
        ps += __shfl_xor(ps, 1); ps += __shfl_xor(ps, 2); ps += __shfl_xor(ps, 4);
        pd += __shfl_xor(pd, 1); pd += __shfl_xor(pd, 2); pd += __shfl_xor(pd, 4);
        if (r < M) {
            store4<OT>(Y + (size_t)r * NOUT + tx * 4, acc[i]);
            if (q == 0) {
                es[r * H + hh] = ps;
                ed[r * H + hh] = pd;
            }
        }
    }
}

// ---------- attention coefficients (fallback path) --------------------------
__global__ __launch_bounds__(256) void attn_kernel(
    const float* __restrict__ h, const float* __restrict__ a_src,
    const float* __restrict__ a_dst, float* __restrict__ es,
    float* __restrict__ ed, int N, int H, int C) {
    int idx = blockIdx.x * blockDim.x + threadIdx.x;
    if (idx >= N * H) return;
    int n = idx / H;
    int hh = idx - n * H;
    const float* hp = h + (size_t)n * H * C + (size_t)hh * C;
    const float* ap = a_src + hh * C;
    const float* bp = a_dst + hh * C;
    float s = 0.f, d = 0.f;
    for (int c = 0; c < C; c += 4) {
        float4 hv = *(const float4*)(hp + c);
        float4 av = *(const float4*)(ap + c);
        float4 bv = *(const float4*)(bp + c);
        s += hv.x * av.x + hv.y * av.y + hv.z * av.z + hv.w * av.w;
        d += hv.x * bv.x + hv.y * bv.y + hv.z * bv.z + hv.w * bv.w;
    }
    es[idx] = s;
    ed[idx] = d;
}

// ---------- edge src/dst with implicit self-loops ---------------------------
__device__ __forceinline__ void edge_sd(const int* __restrict__ ei, int E,
                                        int e, int& s, int& d) {
    if (e < E) {
        s = ei[e];
        d = ei[E + e];
    } else {
        s = e - E;
        d = s;
    }
}

// ---------- CSR build: degree histogram -------------------------------------
__global__ __launch_bounds__(256) void deg_kernel(const int* __restrict__ ei,
                                                  int E, int N,
                                                  int* __restrict__ deg) {
    int e = blockIdx.x * blockDim.x + threadIdx.x;
    if (e >= E + N) return;
    int s, d;
    edge_sd(ei, E, e, s, d);
    atomicAdd(&deg[d], 1);
}

// ---------- CSR build: 3-kernel exclusive scan ------------------------------
__global__ __launch_bounds__(SCAN_BS) void scan1_kernel(
    const int* __restrict__ deg, int* __restrict__ rowptr,
    int* __restrict__ bsum, int N) {
    __shared__ int tmp[SCAN_BS];
    int tid = threadIdx.x;
    int gid = blockIdx.x * SCAN_BS + tid;
    int v = (gid < N) ? deg[gid] : 0;
    tmp[tid] = v;
    __syncthreads();
    for (int off = 1; off < SCAN_BS; off <<= 1) {
        int t = (tid >= off) ? tmp[tid - off] : 0;
        __syncthreads();
        tmp[tid] += t;
        __syncthreads();
    }
    if (gid < N) rowptr[gid] = tmp[tid] - v;  // exclusive
    if (tid == SCAN_BS - 1) bsum[blockIdx.x] = tmp[tid];
}

__global__ void scan2_kernel(int* __restrict__ bsum, int nb) {
    if (threadIdx.x == 0 && blockIdx.x == 0) {
        int acc = 0;
        for (int i = 0; i < nb; ++i) {
            int t = bsum[i];
            bsum[i] = acc;
            acc += t;
        }
    }
}

// also seeds cursor (= rowptr) so the scatter pass needs no separate memcpy
__global__ __launch_bounds__(SCAN_BS) void scan3_kernel(
    int* __restrict__ rowptr, int* __restrict__ cursor,
    const int* __restrict__ bsum, int N, int total) {
    int gid = blockIdx.x * SCAN_BS + threadIdx.x;
    if (gid < N) {
        int v = rowptr[gid] + bsum[blockIdx.x];
        rowptr[gid] = v;
        cursor[gid] = v;
    }
    if (gid == 0) rowptr[N] = total;
}

// ---------- CSR build: scatter src indices ----------------------------------
__global__ __launch_bounds__(256) void scatter_kernel(
    const int* __restrict__ ei, int E, int N, int* __restrict__ cursor,
    int* __restrict__ csrc) {
    int e = blockIdx.x * blockDim.x + threadIdx.x;
    if (e >= E + N) return;
    int s, d;
    edge_sd(ei, E, e, s, d);
    int pos = atomicAdd(&cursor[d], 1);
    csrc[pos] = s;
}

// ---------- fused softmax-aggregate + bias + LN + ELU, D=128, H=4 -----------
// TWO nodes per wave (each 32-lane group owns one full node). 16 edges in
// flight per group (mean degree ~17 -> one dependent memory round for most
// nodes) + 8/4/scalar tails. es gather fused (L2-resident); h fp16.
__global__ __launch_bounds__(256) void aggr_ln128_kernel(
    const int* __restrict__ rowptr, const int* __restrict__ csrc,
    const __half* __restrict__ h, const float* __restrict__ es,
    const float* __restrict__ ed, const float* __restrict__ bias,
    const float* __restrict__ gam, const float* __restrict__ bet,
    float* __restrict__ outp, int N) {
    constexpr int D = 128, H = 4;
    int wave = (blockIdx.x * blockDim.x + threadIdx.x) >> 6;
    int lane = threadIdx.x & 63;
    int grp = lane >> 5;
    int li = lane & 31;
    int d = wave * 2 + grp;
    if (d >= N) return;
    int c = li * 4;          // 4 consecutive channels
    int hh = li >> 3;        // head index
    float edv = ed[d * H + hh];
    float l = 0.f;
    float ax = 0.f, ay = 0.f, az = 0.f, aw = 0.f;
    int k = rowptr[d], end = rowptr[d + 1];
    for (; k + 16 <= end; k += 16) {
        int s[16];
#pragma unroll
        for (int j = 0; j < 16; ++j) s[j] = csrc[k + j];
        float e[16];
#pragma unroll
        for (int j = 0; j < 16; ++j) e[j] = es[s[j] * H + hh];
        uint2 u[16];
#pragma unroll
        for (int j = 0; j < 16; ++j)
            u[j] = *(const uint2*)(h + (size_t)s[j] * D + c);
#pragma unroll
        for (int j = 0; j < 16; ++j) {
            float w = __expf(lrelu(e[j] + edv));
            float2 f0 = __half22float2(*(__half2*)&u[j].x);
            float2 f1 = __half22float2(*(__half2*)&u[j].y);
            l += w;
            ax += w * f0.x; ay += w * f0.y; az += w * f1.x; aw += w * f1.y;
        }
    }
    for (; k + 8 <= end; k += 8) {
        int s[8];
#pragma unroll
        for (int j = 0; j < 8; ++j) s[j] = csrc[k + j];
        float e[8];
#pragma unroll
        for (int j = 0; j < 8; ++j) e[j] = es[s[j] * H + hh];
        uint2 u[8];
#pragma unroll
        for (int j = 0; j < 8; ++j)
            u[j] = *(const uint2*)(h + (size_t)s[j] * D + c);
#pragma unroll
        for (int j = 0; j < 8; ++j) {
            float w = __expf(lrelu(e[j] + edv));
            float2 f0 = __half22float2(*(__half2*)&u[j].x);
            float2 f1 = __half22float2(*(__half2*)&u[j].y);
            l += w;
            ax += w * f0.x; ay += w * f0.y; az += w * f1.x; aw += w * f1.y;
        }
    }
    for (; k + 4 <= end; k += 4) {
        int s[4];
#pragma unroll
        for (int j = 0; j < 4; ++j) s[j] = csrc[k + j];
        float e[4];
#pragma unroll
        for (int j = 0; j < 4; ++j) e[j] = es[s[j] * H + hh];
        uint2 u[4];
#pragma unroll
        for (int j = 0; j < 4; ++j)
            u[j] = *(const uint2*)(h + (size_t)s[j] * D + c);
#pragma unroll
        for (int j = 0; j < 4; ++j) {
            float w = __expf(lrelu(e[j] + edv));
            float2 f0 = __half22float2(*(__half2*)&u[j].x);
            float2 f1 = __half22float2(*(__half2*)&u[j].y);
            l += w;
            ax += w * f0.x; ay += w * f0.y; az += w * f1.x; aw += w * f1.y;
        }
    }
    for (; k < end; ++k) {
        int s = csrc[k];
        float w = __expf(lrelu(es[s * H + hh] + edv));
        uint2 u = *(const uint2*)(h + (size_t)s * D + c);
        float2 f0 = __half22float2(*(__half2*)&u.x);
        float2 f1 = __half22float2(*(__half2*)&u.y);
        l += w;
        ax += w * f0.x; ay += w * f0.y; az += w * f1.x; aw += w * f1.y;
    }
    float rl = 1.f / (l + 1e-16f);
    float4 b4 = *(const float4*)(bias + c);
    float v0 = ax * rl + b4.x;
    float v1 = ay * rl + b4.y;
    float v2 = az * rl + b4.z;
    float v3 = aw * rl + b4.w;
    // LayerNorm over 128 channels within the 32-lane group
    float s = v0 + v1 + v2 + v3;
    float ss = v0 * v0 + v1 * v1 + v2 * v2 + v3 * v3;
    for (int off = 16; off; off >>= 1) {
        s += __shfl_xor(s, off);
        ss += __shfl_xor(ss, off);
    }
    float mean = s / D;
    float var = ss / D - mean * mean;
    float rstd = rsqrtf(var + 1e-5f);
    float4 g4 = *(const float4*)(gam + c);
    float4 t4 = *(const float4*)(bet + c);
    float4 o;
    o.x = (v0 - mean) * rstd * g4.x + t4.x;
    o.y = (v1 - mean) * rstd * g4.y + t4.y;
    o.z = (v2 - mean) * rstd * g4.z + t4.z;
    o.w = (v3 - mean) * rstd * g4.w + t4.w;
    o.x = o.x > 0.f ? o.x : expm1f(o.x);
    o.y = o.y > 0.f ? o.y : expm1f(o.y);
    o.z = o.z > 0.f ? o.z : expm1f(o.z);
    o.w = o.w > 0.f ? o.w : expm1f(o.w);
    *(float4*)(outp + (size_t)d * D + c) = o;
}

// ---------- layer 3: aggregate (D=32) + bias + LN + ELU + pool --------------
// Two nodes per wave; fused es; 16-deep main tier (+8/4/scalar tails).
__global__ __launch_bounds__(256) void aggr_ln32_pool_kernel(
    const int* __restrict__ rowptr, const int* __restrict__ csrc,
    const __half* __restrict__ h, const float* __restrict__ es,
    const float* __restrict__ ed, const float* __restrict__ bias,
    const float* __restrict__ gam, const float* __restrict__ bet,
    const int* __restrict__ batch, float* __restrict__ psum,
    unsigned* __restrict__ pmax, float* __restrict__ cnt, int N) {
    constexpr int D = 32;
    int wave = (blockIdx.x * blockDim.x + threadIdx.x) >> 6;
    int lane = threadIdx.x & 63;
    int half = lane >> 5;
    int c = lane & 31;
    int d = wave * 2 + half;
    if (d >= N) return;
    float edv = ed[d];
    float l = 0.f, acc = 0.f;
    int k = rowptr[d], end = rowptr[d + 1];
    for (; k + 16 <= end; k += 16) {
        int s[16];
#pragma unroll
        for (int j = 0; j < 16; ++j) s[j] = csrc[k + j];
        float e[16];
#pragma unroll
        for (int j = 0; j < 16; ++j) e[j] = es[s[j]];
        float hv[16];
#pragma unroll
        for (int j = 0; j < 16; ++j)
            hv[j] = __half2float(h[(size_t)s[j] * D + c]);
#pragma unroll
        for (int j = 0; j < 16; ++j) {
            float w = __expf(lrelu(e[j] + edv));
            l += w;
            acc += w * hv[j];
        }
    }
    for (; k + 8 <= end; k += 8) {
        int s[8];
#pragma unroll
        for (int j = 0; j < 8; ++j) s[j] = csrc[k + j];
        float e[8];
#pragma unroll
        for (int j = 0; j < 8; ++j) e[j] = es[s[j]];
        float hv[8];
#pragma unroll
        for (int j = 0; j < 8; ++j)
            hv[j] = __half2float(h[(size_t)s[j] * D + c]);
#pragma unroll
        for (int j = 0; j < 8; ++j) {
            float w = __expf(lrelu(e[j] + edv));
            l += w;
            acc += w * hv[j];
        }
    }
    for (; k + 4 <= end; k += 4) {
        int s[4];
#pragma unroll
        for (int j = 0; j < 4; ++j) s[j] = csrc[k + j];
        float e[4];
#pragma unroll
        for (int j = 0; j < 4; ++j) e[j] = es[s[j]];
        float hv[4];
#pragma unroll
        for (int j = 0; j < 4; ++j)
            hv[j] = __half2float(h[(size_t)s[j] * D + c]);
#pragma unroll
        for (int j = 0; j < 4; ++j) {
            float w = __expf(lrelu(e[j] + edv));
            l += w;
            acc += w * hv[j];
        }
    }
    for (; k < end; ++k) {
        int s = csrc[k];
        float w = __expf(lrelu(es[s] + edv));
        l += w;
        acc += w * __half2float(h[(size_t)s * D + c]);
    }
    float v = acc / (l + 1e-16f) + bias[c];
    // LayerNorm within the 32-lane half
    float sm = v, ss = v * v;
    for (int off = 16; off; off >>= 1) {
        sm += __shfl_xor(sm, off);
        ss += __shfl_xor(ss, off);
    }
    float mean = sm / D;
    float var = ss / D - mean * mean;
    float rstd = rsqrtf(var + 1e-5f);
    float o = (v - mean) * rstd * gam[c] + bet[c];
    o = o > 0.f ? o : expm1f(o);
    int g = batch[d];
    atomicAdd(&psum[g * D + c], o);
    atomicMax(&pmax[g * D + c], encf(o));
    if (c == 0) atomicAdd(&cnt[g], 1.0f);
}

// ---------- fallback aggregation (online softmax, generic shapes) -----------
__global__ __launch_bounds__(256) void aggr_csr_kernel(
    const int* __restrict__ rowptr, const int* __restrict__ csrc,
    const float* __restrict__ h, const float* __restrict__ es,
    const float* __restrict__ ed, float* __restrict__ outp, int N, int H,
    int C) {
    int D = H * C;
    int wave = (blockIdx.x * blockDim.x + threadIdx.x) >> 6;
    int lane = threadIdx.x & 63;
    if (wave >= N) return;
    int d = wave;
    int c0 = lane, c1 = lane + 64;
    bool a0 = c0 < D, a1 = c1 < D;
    int h0 = a0 ? c0 / C : 0;
    int h1 = a1 ? c1 / C : 0;
    float edv0 = a0 ? ed[d * H + h0] : 0.f;
    float edv1 = a1 ? ed[d * H + h1] : 0.f;
    float m0 = -INFINITY, m1 = -INFINITY;
    float l0 = 0.f, l1 = 0.f, acc0 = 0.f, acc1 = 0.f;
    int beg = rowptr[d], end = rowptr[d + 1];
    for (int k = beg; k < end; ++k) {
        int s = csrc[k];
        const float* hp = h + (size_t)s * D;
        if (a0) {
            float v = lrelu(es[s * H + h0] + edv0);
            float nm = fmaxf(m0, v);
            float sc = __expf(m0 - nm);
            float w = __expf(v - nm);
            l0 = l0 * sc + w;
            acc0 = acc0 * sc + w * hp[c0];
            m0 = nm;
        }
        if (a1) {
            float v = lrelu(es[s * H + h1] + edv1);
            float nm = fmaxf(m1, v);
            float sc = __expf(m1 - nm);
            float w = __expf(v - nm);
            l1 = l1 * sc + w;
            acc1 = acc1 * sc + w * hp[c1];
            m1 = nm;
        }
    }
    if (a0) outp[(size_t)d * D + c0] = acc0 / (l0 + 1e-16f);
    if (a1) outp[(size_t)d * D + c1] = acc1 / (l1 + 1e-16f);
}

// ---------- bias + LayerNorm + ELU (fallback path) --------------------------
__global__ __launch_bounds__(64) void ln_elu_kernel(
    const float* __restrict__ in, const float* __restrict__ bias,
    const float* __restrict__ gam, const float* __restrict__ bet,
    float* __restrict__ outp, int D) {
    int n = blockIdx.x;
    int lane = threadIdx.x;  // blockDim = 64
    int c0 = lane, c1 = lane + 64;
    bool a0 = c0 < D, a1 = c1 < D;
    float v0 = 0.f, v1 = 0.f;
    if (a0) v0 = in[(size_t)n * D + c0] + bias[c0];
    if (a1) v1 = in[(size_t)n * D + c1] + bias[c1];
    float s = v0 + v1;
    float ss = v0 * v0 + v1 * v1;
    for (int off = 32; off; off >>= 1) {
        s += __shfl_xor(s, off);
        ss += __shfl_xor(ss, off);
    }
    float mean = s / D;
    float var = ss / D - mean * mean;
    float rstd = rsqrtf(var + 1e-5f);
    if (a0) {
        float o = (v0 - mean) * rstd * gam[c0] + bet[c0];
        outp[(size_t)n * D + c0] = o > 0.f ? o : expm1f(o);
    }
    if (a1) {
        float o = (v1 - mean) * rstd * gam[c1] + bet[c1];
        outp[(size_t)n * D + c1] = o > 0.f ? o : expm1f(o);
    }
}

// ---------- graph pooling (fallback path) -----------------------------------
__global__ __launch_bounds__(256) void pool_kernel(
    const float* __restrict__ h, const int* __restrict__ batch, int N, int C,
    float* __restrict__ psum, unsigned* __restrict__ pmax,
    float* __restrict__ cnt) {
    int idx = blockIdx.x * blockDim.x + threadIdx.x;
    if (idx >= N * C) return;
    int n = idx / C;
    int c = idx - n * C;
    int g = batch[n];
    float v = h[(size_t)n * C + c];
    atomicAdd(&psum[g * C + c], v);
    atomicMax(&pmax[g * C + c], encf(v));
    if (c == 0) atomicAdd(&cnt[g], 1.0f);
}

// ---------- classifier MLP: one block (1 wave) per graph --------------------
__global__ __launch_bounds__(64) void mlp_kernel(
    const float* __restrict__ psum, const unsigned* __restrict__ pmax,
    const float* __restrict__ cnt, const float* __restrict__ cW1,
    const float* __restrict__ cb1, const float* __restrict__ cW2,
    const float* __restrict__ cb2, const float* __restrict__ cW3,
    const float* __restrict__ cb3, float* __restrict__ outp, int C) {
    __shared__ float f[64];
    __shared__ float t1[32];
    __shared__ float t2[16];
    int g = blockIdx.x;
    int t = threadIdx.x;
    float c = fmaxf(cnt[g], 1.0f);
    if (t < C) {
        f[t] = psum[g * C + t] / c;
    } else if (t < 2 * C) {
        unsigned k = pmax[g * C + (t - C)];
        f[t] = (k == 0u) ? -INFINITY : decf(k);
    }
    __syncthreads();
    if (t < 32) {
        float a = cb1[t];
        for (int i = 0; i < 64; ++i) a += f[i] * cW1[t * 64 + i];
        t1[t] = fmaxf(a, 0.f);
    }
    __syncthreads();
    if (t < 16) {
        float a = cb2[t];
        for (int i = 0; i < 32; ++i) a += t1[i] * cW2[t * 32 + i];
        t2[t] = fmaxf(a, 0.f);
    }
    __syncthreads();
    if (t == 0) {
        float a = cb3[0];
        for (int i = 0; i < 16; ++i) a += t2[i] * cW3[i];
        outp[g] = a;
    }
}

// ---------------------------------------------------------------------------
extern "C" void kernel_launch(void* const* d_in, const int* in_sizes, int n_in,
                              void* d_out, int out_size, void* d_ws,
                              size_t ws_size, hipStream_t stream) {
    const float* x = (const float*)d_in[0];
    const int* ei = (const int*)d_in[1];
    const int* batch = (const int*)d_in[2];
    const float* W1 = (const float*)d_in[4];
    const float* as1 = (const float*)d_in[5];
    const float* ad1 = (const float*)d_in[6];
    const float* b1 = (const float*)d_in[7];
    const float* g1 = (const float*)d_in[8];
    const float* be1 = (const float*)d_in[9];
    const float* W2 = (const float*)d_in[10];
    const float* as2 = (const float*)d_in[11];
    const float* ad2 = (const float*)d_in[12];
    const float* b2 = (const float*)d_in[13];
    const float* g2 = (const float*)d_in[14];
    const float* be2 = (const float*)d_in[15];
    const float* W3 = (const float*)d_in[16];
    const float* as3 = (const float*)d_in[17];
    const float* ad3 = (const float*)d_in[18];
    const float* b3 = (const float*)d_in[19];
    const float* g3 = (const float*)d_in[20];
    const float* be3 = (const float*)d_in[21];
    const float* cW1 = (const float*)d_in[22];
    const float* cb1 = (const float*)d_in[23];
    const float* cW2 = (const float*)d_in[24];
    const float* cb2 = (const float*)d_in[25];
    const float* cW3 = (const float*)d_in[26];
    const float* cb3 = (const float*)d_in[27];

    const int N = in_sizes[2];            // 50000
    const int E = in_sizes[1] / 2;        // 800000
    const int F0 = in_sizes[0] / N;       // 32
    const int Hd = in_sizes[19];          // 32 (b3)
    const int H = in_sizes[5] / Hd;       // 4
    const int D = H * Hd;                 // 128
    const int H3 = in_sizes[17] / Hd;     // 1
    const int G = out_size;               // 512
    const int EN = E + N;
    const bool shapes_ok = (F0 == 32 && Hd == 32 && H == 4 && D == 128 && H3 == 1);

    // -------- workspace carve-out (256B aligned) --------
    char* w = (char*)d_ws;
    size_t off = 0;
    auto carve = [&](size_t bytes) -> void* {
        void* p = w + off;
        off = (off + bytes + 255) & ~(size_t)255;
        return p;
    };
    float* Q = (float*)carve((size_t)N * D * 4);      // fallback fp32 staging
    __half* Qh = (__half*)Q;                          // main path fp16 staging
    float* R = (float*)carve((size_t)N * D * 4);      // fallback scratch
    float* P = (float*)carve((size_t)N * D * 4);      // activations
    float* es = (float*)carve((size_t)N * H * 4);
    float* ed = (float*)carve((size_t)N * H * 4);
    int* rowptr = (int*)carve((size_t)(N + 1) * 4);
    int* cursor = (int*)carve((size_t)N * 4);
    int* csrc = (int*)carve((size_t)EN * 4);
    int* bsum = (int*)carve((size_t)CDIV(N, SCAN_BS) * 4);
    float* psum = (float*)carve((size_t)G * Hd * 4);
    unsigned* pmax = (unsigned*)carve((size_t)G * Hd * 4);
    float* cnt = (float*)carve((size_t)G * 4);
    (void)ws_size;
    (void)n_in;

    const int BLK = 256;
    const int nb = CDIV(N, SCAN_BS);

    // ---------------- CSR build (once, reused by all 3 layers) -------------
    hipMemsetAsync(cursor, 0, (size_t)N * 4, stream);  // use cursor as deg
    deg_kernel<<<CDIV(EN, BLK), BLK, 0, stream>>>(ei, E, N, cursor);
    scan1_kernel<<<nb, SCAN_BS, 0, stream>>>(cursor, rowptr, bsum, N);
    scan2_kernel<<<1, 64, 0, stream>>>(bsum, nb);
    scan3_kernel<<<nb, SCAN_BS, 0, stream>>>(rowptr, cursor, bsum, N, EN);
    scatter_kernel<<<CDIV(EN, BLK), BLK, 0, stream>>>(ei, E, N, cursor, csrc);

    // pooling buffers (used at the end; clear early so it overlaps)
    hipMemsetAsync(psum, 0, (size_t)G * Hd * 4, stream);
    hipMemsetAsync(pmax, 0, (size_t)G * Hd * 4, stream);
    hipMemsetAsync(cnt, 0, (size_t)G * 4, stream);

    if (shapes_ok) {
        // layer 1
        gemm_attn<32, 128, 8, 4, __half><<<CDIV(N, 64), 256, 0, stream>>>(
            x, W1, as1, ad1, Qh, es, ed, N);
        aggr_ln128_kernel<<<CDIV(N, 8), 256, 0, stream>>>(
            rowptr, csrc, Qh, es, ed, b1, g1, be1, P, N);
        // layer 2
        gemm_attn<128, 128, 8, 4, __half><<<CDIV(N, 64), 256, 0, stream>>>(
            P, W2, as2, ad2, Qh, es, ed, N);
        aggr_ln128_kernel<<<CDIV(N, 8), 256, 0, stream>>>(
            rowptr, csrc, Qh, es, ed, b2, g2, be2, P, N);
        // layer 3 (+ fused pooling)
        gemm_attn<128, 32, 4, 1, __half><<<CDIV(N, 128), 256, 0, stream>>>(
            P, W3, as3, ad3, Qh, es, ed, N);
        aggr_ln32_pool_kernel<<<CDIV(N, 8), 256, 0, stream>>>(
            rowptr, csrc, Qh, es, ed, b3, g3, be3, batch, psum, pmax, cnt, N);
    } else {
        // generic fallback path (all fp32)
        gemm_kernel<<<CDIV(N * D, BLK), BLK, 0, stream>>>(x, W1, Q, N, F0, D);
        attn_kernel<<<CDIV(N * H, BLK), BLK, 0, stream>>>(Q, as1, ad1, es, ed, N, H, Hd);
        aggr_csr_kernel<<<CDIV(N, 4), BLK, 0, stream>>>(rowptr, csrc, Q, es, ed, R, N, H, Hd);
        ln_elu_kernel<<<N, 64, 0, stream>>>(R, b1, g1, be1, P, D);
        gemm_kernel<<<CDIV(N * D, BLK), BLK, 0, stream>>>(P, W2, Q, N, D, D);
        attn_kernel<<<CDIV(N * H, BLK), BLK, 0, stream>>>(Q, as2, ad2, es, ed, N, H, Hd);
        aggr_csr_kernel<<<CDIV(N, 4), BLK, 0, stream>>>(rowptr, csrc, Q, es, ed, R, N, H, Hd);
        ln_elu_kernel<<<N, 64, 0, stream>>>(R, b2, g2, be2, P, D);
        gemm_kernel<<<CDIV(N * Hd, BLK), BLK, 0, stream>>>(P, W3, Q, N, D, Hd);
        attn_kernel<<<CDIV(N * H3, BLK), BLK, 0, stream>>>(Q, as3, ad3, es, ed, N, H3, Hd);
        aggr_csr_kernel<<<CDIV(N, 4), BLK, 0, stream>>>(rowptr, csrc, Q, es, ed, R, N, H3, Hd);
        ln_elu_kernel<<<N, 64, 0, stream>>>(R, b3, g3, be3, P, Hd);
        pool_kernel<<<CDIV(N * Hd, BLK), BLK, 0, stream>>>(P, batch, N, Hd, psum, pmax, cnt);
    }

    mlp_kernel<<<G, 64, 0, stream>>>(psum, pmax, cnt, cW1, cb1, cW2, cb2, cW3,
                                     cb3, (float*)d_out, Hd);
}

// Round 12
// 405.714 us; speedup vs baseline: 1.2361x; 1.2361x over previous
//
#include <hip/hip_runtime.h>
#include <hip/hip_fp16.h>
#include <math.h>

#define CDIV(a, b) (((a) + (b) - 1) / (b))
#define SCAN_BS 1024

// ---------- float <-> monotone-unsigned encoding for atomicMax on floats ----
__device__ __forceinline__ unsigned encf(float v) {
    unsigned u = __float_as_uint(v);
    return (u & 0x80000000u) ? ~u : (u | 0x80000000u);
}
__device__ __forceinline__ float decf(unsigned k) {
    unsigned u = (k & 0x80000000u) ? (k ^ 0x80000000u) : ~k;
    return __uint_as_float(u);
}

__device__ __forceinline__ float lrelu(float v) {
    return v > 0.f ? v : 0.2f * v;
}

// ---------- typed 4-element store (fp32 or fp16 output) ---------------------
template <typename OT>
__device__ __forceinline__ void store4(OT* p, const float* a);
template <>
__device__ __forceinline__ void store4<float>(float* p, const float* a) {
    *(float4*)p = *(const float4*)a;
}
template <>
__device__ __forceinline__ void store4<__half>(__half* p, const float* a) {
    __half2 p0 = __floats2half2_rn(a[0], a[1]);
    __half2 p1 = __floats2half2_rn(a[2], a[3]);
    uint2 u;
    u.x = *(unsigned*)&p0;
    u.y = *(unsigned*)&p1;
    *(uint2*)p = u;
}

// ---------- naive GEMM fallback (only if shapes are unexpected) -------------
__global__ __launch_bounds__(256) void gemm_kernel(
    const float* __restrict__ X, const float* __restrict__ W,
    float* __restrict__ Y, int M, int K, int Nout) {
    int idx = blockIdx.x * blockDim.x + threadIdx.x;
    if (idx >= M * Nout) return;
    int row = idx / Nout;
    int col = idx - row * Nout;
    const float* xr = X + (size_t)row * K;
    const float* wc = W + col;
    float acc = 0.f;
    for (int k = 0; k < K; k += 4) {
        float4 xv = *(const float4*)(xr + k);
        acc += xv.x * wc[(size_t)(k + 0) * Nout];
        acc += xv.y * wc[(size_t)(k + 1) * Nout];
        acc += xv.z * wc[(size_t)(k + 2) * Nout];
        acc += xv.w * wc[(size_t)(k + 3) * Nout];
    }
    Y[idx] = acc;
}

// ---------- LDS-tiled GEMM + fused attention dot-products -------------------
template <int K, int NOUT, int RPT, int H, typename OT>
__global__ __launch_bounds__(256) void gemm_attn(
    const float* __restrict__ X, const float* __restrict__ W,
    const float* __restrict__ asrc, const float* __restrict__ adst,
    OT* __restrict__ Y, float* __restrict__ es, float* __restrict__ ed,
    int M) {
    constexpr int TX = NOUT / 4;
    constexpr int TY = 256 / TX;
    constexpr int ROWS = TY * RPT;
    constexpr int KB = (K > 64) ? 64 : K;
    constexpr int C = 32;       // head dim
    constexpr int GP = C / 4;   // 8 threads per (row, head)
    __shared__ float Wl[KB * NOUT];
    const int t = threadIdx.x;
    const int tx = t % TX;
    const int ty = t / TX;
    const int row0 = blockIdx.x * ROWS + ty;
    const float* xp[RPT];
#pragma unroll
    for (int i = 0; i < RPT; ++i) {
        int r = row0 + TY * i;
        xp[i] = X + (size_t)(r < M ? r : (M - 1)) * K;
    }
    float acc[RPT][4] = {};
    for (int kb = 0; kb < K; kb += KB) {
        constexpr int NLD = KB * NOUT / 4 / 256;
        const float4* wg = (const float4*)(W + (size_t)kb * NOUT);
#pragma unroll
        for (int j = 0; j < NLD; ++j) {
            int idx = t + 256 * j;
            ((float4*)Wl)[idx] = wg[idx];
        }
        __syncthreads();
#pragma unroll 2
        for (int k4 = 0; k4 < KB / 4; ++k4) {
            float4 xv[RPT];
#pragma unroll
            for (int i = 0; i < RPT; ++i)
                xv[i] = *(const float4*)(xp[i] + kb + 4 * k4);
            float4 wv[4];
#pragma unroll
            for (int j = 0; j < 4; ++j)
                wv[j] = *(const float4*)&Wl[(4 * k4 + j) * NOUT + tx * 4];
#pragma unroll
            for (int i = 0; i < RPT; ++i) {
                acc[i][0] += xv[i].x * wv[0].x + xv[i].y * wv[1].x +
                             xv[i].z * wv[2].x + xv[i].w * wv[3].x;
                acc[i][1] += xv[i].x * wv[0].y + xv[i].y * wv[1].y +
                             xv[i].z * wv[2].y + xv[i].w * wv[3].y;
                acc[i][2] += xv[i].x * wv[0].z + xv[i].y * wv[1].z +
                             xv[i].z * wv[2].z + xv[i].w * wv[3].z;
                acc[i][3] += xv[i].x * wv[0].w + xv[i].y * wv[1].w +
                             xv[i].z * wv[2].w + xv[i].w * wv[3].w;
            }
        }
        __syncthreads();
    }
    const int hh = tx / GP;      // head of this thread's 4 cols
    const int q = tx % GP;       // position within head
    float asv[4], adv[4];
#pragma unroll
    for (int j = 0; j < 4; ++j) {
        asv[j] = asrc[hh * C + q * 4 + j];
        adv[j] = adst[hh * C + q * 4 + j];
    }
#pragma unroll
    for (int i = 0; i < RPT; ++i) {
        int r = row0 + TY * i;
        float ps = acc[i][0] * asv[0] + acc[i][1] * asv[1] +
                   acc[i][2] * asv[2] + acc[i][3] * asv[3];
        float pd = acc[i][0] * adv[0] + acc[i][1] * adv[1] +
                   acc[i][2] * adv[2] + acc[i][3] * adv[3];
        ps += __shfl_xor(ps, 1); ps += __shfl_xor(ps, 2); ps += __shfl_xor(ps, 4);
        pd += __shfl_xor(pd, 1); pd += __shfl_xor(pd, 2); pd += __shfl_xor(pd, 4);
        if (r < M) {
            store4<OT>(Y + (size_t)r * NOUT + tx * 4, acc[i]);
            if (q == 0) {
                es[r * H + hh] = ps;
                ed[r * H + hh] = pd;
            }
        }
    }
}

// ---------- attention coefficients (fallback path) --------------------------
__global__ __launch_bounds__(256) void attn_kernel(
    const float* __restrict__ h, const float* __restrict__ a_src,
    const float* __restrict__ a_dst, float* __restrict__ es,
    float* __restrict__ ed, int N, int H, int C) {
    int idx = blockIdx.x * blockDim.x + threadIdx.x;
    if (idx >= N * H) return;
    int n = idx / H;
    int hh = idx - n * H;
    const float* hp = h + (size_t)n * H * C + (size_t)hh * C;
    const float* ap = a_src + hh * C;
    const float* bp = a_dst + hh * C;
    float s = 0.f, d = 0.f;
    for (int c = 0; c < C; c += 4) {
        float4 hv = *(const float4*)(hp + c);
        float4 av = *(const float4*)(ap + c);
        float4 bv = *(const float4*)(bp + c);
        s += hv.x * av.x + hv.y * av.y + hv.z * av.z + hv.w * av.w;
        d += hv.x * bv.x + hv.y * bv.y + hv.z * bv.z + hv.w * bv.w;
    }
    es[idx] = s;
    ed[idx] = d;
}

// ---------- edge src/dst with implicit self-loops ---------------------------
__device__ __forceinline__ void edge_sd(const int* __restrict__ ei, int E,
                                        int e, int& s, int& d) {
    if (e < E) {
        s = ei[e];
        d = ei[E + e];
    } else {
        s = e - E;
        d = s;
    }
}

// ---------- CSR build: degree histogram -------------------------------------
__global__ __launch_bounds__(256) void deg_kernel(const int* __restrict__ ei,
                                                  int E, int N,
                                                  int* __restrict__ deg) {
    int e = blockIdx.x * blockDim.x + threadIdx.x;
    if (e >= E + N) return;
    int s, d;
    edge_sd(ei, E, e, s, d);
    atomicAdd(&deg[d], 1);
}

// ---------- CSR build: 3-kernel exclusive scan ------------------------------
__global__ __launch_bounds__(SCAN_BS) void scan1_kernel(
    const int* __restrict__ deg, int* __restrict__ rowptr,
    int* __restrict__ bsum, int N) {
    __shared__ int tmp[SCAN_BS];
    int tid = threadIdx.x;
    int gid = blockIdx.x * SCAN_BS + tid;
    int v = (gid < N) ? deg[gid] : 0;
    tmp[tid] = v;
    __syncthreads();
    for (int off = 1; off < SCAN_BS; off <<= 1) {
        int t = (tid >= off) ? tmp[tid - off] : 0;
        __syncthreads();
        tmp[tid] += t;
        __syncthreads();
    }
    if (gid < N) rowptr[gid] = tmp[tid] - v;  // exclusive
    if (tid == SCAN_BS - 1) bsum[blockIdx.x] = tmp[tid];
}

__global__ void scan2_kernel(int* __restrict__ bsum, int nb) {
    if (threadIdx.x == 0 && blockIdx.x == 0) {
        int acc = 0;
        for (int i = 0; i < nb; ++i) {
            int t = bsum[i];
            bsum[i] = acc;
            acc += t;
        }
    }
}

// also seeds cursor (= rowptr) so the scatter pass needs no separate memcpy
__global__ __launch_bounds__(SCAN_BS) void scan3_kernel(
    int* __restrict__ rowptr, int* __restrict__ cursor,
    const int* __restrict__ bsum, int N, int total) {
    int gid = blockIdx.x * SCAN_BS + threadIdx.x;
    if (gid < N) {
        int v = rowptr[gid] + bsum[blockIdx.x];
        rowptr[gid] = v;
        cursor[gid] = v;
    }
    if (gid == 0) rowptr[N] = total;
}

// ---------- CSR build: scatter src indices ----------------------------------
__global__ __launch_bounds__(256) void scatter_kernel(
    const int* __restrict__ ei, int E, int N, int* __restrict__ cursor,
    int* __restrict__ csrc) {
    int e = blockIdx.x * blockDim.x + threadIdx.x;
    if (e >= E + N) return;
    int s, d;
    edge_sd(ei, E, e, s, d);
    int pos = atomicAdd(&cursor[d], 1);
    csrc[pos] = s;
}

// ---------- fused softmax-aggregate + bias + LN + ELU, D=128, H=4 -----------
// TWO nodes per wave (each 32-lane group owns one full node). 8 edges in
// flight per group (+4/scalar tails) — the empirically optimal depth.
// es gather fused (L2-resident); h fp16; math fp32.
__global__ __launch_bounds__(256) void aggr_ln128_kernel(
    const int* __restrict__ rowptr, const int* __restrict__ csrc,
    const __half* __restrict__ h, const float* __restrict__ es,
    const float* __restrict__ ed, const float* __restrict__ bias,
    const float* __restrict__ gam, const float* __restrict__ bet,
    float* __restrict__ outp, int N) {
    constexpr int D = 128, H = 4;
    int wave = (blockIdx.x * blockDim.x + threadIdx.x) >> 6;
    int lane = threadIdx.x & 63;
    int grp = lane >> 5;
    int li = lane & 31;
    int d = wave * 2 + grp;
    if (d >= N) return;
    int c = li * 4;          // 4 consecutive channels
    int hh = li >> 3;        // head index
    float edv = ed[d * H + hh];
    float l = 0.f;
    float ax = 0.f, ay = 0.f, az = 0.f, aw = 0.f;
    int k = rowptr[d], end = rowptr[d + 1];
    for (; k + 8 <= end; k += 8) {
        int s[8];
#pragma unroll
        for (int j = 0; j < 8; ++j) s[j] = csrc[k + j];
        float e[8];
#pragma unroll
        for (int j = 0; j < 8; ++j) e[j] = es[s[j] * H + hh];
        uint2 u[8];
#pragma unroll
        for (int j = 0; j < 8; ++j)
            u[j] = *(const uint2*)(h + (size_t)s[j] * D + c);
#pragma unroll
        for (int j = 0; j < 8; ++j) {
            float w = __expf(lrelu(e[j] + edv));
            float2 f0 = __half22float2(*(__half2*)&u[j].x);
            float2 f1 = __half22float2(*(__half2*)&u[j].y);
            l += w;
            ax += w * f0.x; ay += w * f0.y; az += w * f1.x; aw += w * f1.y;
        }
    }
    for (; k + 4 <= end; k += 4) {
        int s[4];
#pragma unroll
        for (int j = 0; j < 4; ++j) s[j] = csrc[k + j];
        float e[4];
#pragma unroll
        for (int j = 0; j < 4; ++j) e[j] = es[s[j] * H + hh];
        uint2 u[4];
#pragma unroll
        for (int j = 0; j < 4; ++j)
            u[j] = *(const uint2*)(h + (size_t)s[j] * D + c);
#pragma unroll
        for (int j = 0; j < 4; ++j) {
            float w = __expf(lrelu(e[j] + edv));
            float2 f0 = __half22float2(*(__half2*)&u[j].x);
            float2 f1 = __half22float2(*(__half2*)&u[j].y);
            l += w;
            ax += w * f0.x; ay += w * f0.y; az += w * f1.x; aw += w * f1.y;
        }
    }
    for (; k < end; ++k) {
        int s = csrc[k];
        float w = __expf(lrelu(es[s * H + hh] + edv));
        uint2 u = *(const uint2*)(h + (size_t)s * D + c);
        float2 f0 = __half22float2(*(__half2*)&u.x);
        float2 f1 = __half22float2(*(__half2*)&u.y);
        l += w;
        ax += w * f0.x; ay += w * f0.y; az += w * f1.x; aw += w * f1.y;
    }
    float rl = 1.f / (l + 1e-16f);
    float4 b4 = *(const float4*)(bias + c);
    float v0 = ax * rl + b4.x;
    float v1 = ay * rl + b4.y;
    float v2 = az * rl + b4.z;
    float v3 = aw * rl + b4.w;
    // LayerNorm over 128 channels within the 32-lane group
    float s = v0 + v1 + v2 + v3;
    float ss = v0 * v0 + v1 * v1 + v2 * v2 + v3 * v3;
    for (int off = 16; off; off >>= 1) {
        s += __shfl_xor(s, off);
        ss += __shfl_xor(ss, off);
    }
    float mean = s / D;
    float var = ss / D - mean * mean;
    float rstd = rsqrtf(var + 1e-5f);
    float4 g4 = *(const float4*)(gam + c);
    float4 t4 = *(const float4*)(bet + c);
    float4 o;
    o.x = (v0 - mean) * rstd * g4.x + t4.x;
    o.y = (v1 - mean) * rstd * g4.y + t4.y;
    o.z = (v2 - mean) * rstd * g4.z + t4.z;
    o.w = (v3 - mean) * rstd * g4.w + t4.w;
    o.x = o.x > 0.f ? o.x : expm1f(o.x);
    o.y = o.y > 0.f ? o.y : expm1f(o.y);
    o.z = o.z > 0.f ? o.z : expm1f(o.z);
    o.w = o.w > 0.f ? o.w : expm1f(o.w);
    *(float4*)(outp + (size_t)d * D + c) = o;
}

// ---------- layer 3: aggregate (D=32) + bias + LN + ELU + pool --------------
// Two nodes per wave; fused es; 8-deep (+4/scalar tails). Pooling goes
// through a block-level LDS reduction: batch[] is sorted, so the block's 8
// consecutive nodes span 1-2 graphs -> accumulate into 2 LDS graph slots
// (rare off-range nodes spill to global), then flush <=2x32 device-scope
// atomics per block instead of 8x32. This attacks the cross-XCD atomic
// line-bouncing evidenced by WRITE_SIZE=20MB vs a 128KB pooling footprint.
__global__ __launch_bounds__(256) void aggr_ln32_pool_kernel(
    const int* __restrict__ rowptr, const int* __restrict__ csrc,
    const __half* __restrict__ h, const float* __restrict__ es,
    const float* __restrict__ ed, const float* __restrict__ bias,
    const float* __restrict__ gam, const float* __restrict__ bet,
    const int* __restrict__ batch, float* __restrict__ psum,
    unsigned* __restrict__ pmax, float* __restrict__ cnt, int N) {
    constexpr int D = 32;
    __shared__ float lsum[2][32];
    __shared__ unsigned lmax[2][32];
    __shared__ float lcnt[2];
    __shared__ int g0s;
    int tid = threadIdx.x;
    int wave = (blockIdx.x * blockDim.x + tid) >> 6;
    int lane = tid & 63;
    int half = lane >> 5;
    int c = lane & 31;
    int d = wave * 2 + half;
    int dbase = blockIdx.x * 8;  // first node of this block
    if (tid < 64) {
        lsum[tid >> 5][tid & 31] = 0.f;
        lmax[tid >> 5][tid & 31] = 0u;
    }
    if (tid < 2) lcnt[tid] = 0.f;
    if (tid == 0) g0s = batch[dbase < N ? dbase : (N - 1)];
    __syncthreads();
    int g0 = g0s;
    bool active = d < N;
    if (active) {
        float edv = ed[d];
        float l = 0.f, acc = 0.f;
        int k = rowptr[d], end = rowptr[d + 1];
        for (; k + 8 <= end; k += 8) {
            int s[8];
#pragma unroll
            for (int j = 0; j < 8; ++j) s[j] = csrc[k + j];
            float e[8];
#pragma unroll
            for (int j = 0; j < 8; ++j) e[j] = es[s[j]];
            float hv[8];
#pragma unroll
            for (int j = 0; j < 8; ++j)
                hv[j] = __half2float(h[(size_t)s[j] * D + c]);
#pragma unroll
            for (int j = 0; j < 8; ++j) {
                float w = __expf(lrelu(e[j] + edv));
                l += w;
                acc += w * hv[j];
            }
        }
        for (; k + 4 <= end; k += 4) {
            int s[4];
#pragma unroll
            for (int j = 0; j < 4; ++j) s[j] = csrc[k + j];
            float e[4];
#pragma unroll
            for (int j = 0; j < 4; ++j) e[j] = es[s[j]];
            float hv[4];
#pragma unroll
            for (int j = 0; j < 4; ++j)
                hv[j] = __half2float(h[(size_t)s[j] * D + c]);
#pragma unroll
            for (int j = 0; j < 4; ++j) {
                float w = __expf(lrelu(e[j] + edv));
                l += w;
                acc += w * hv[j];
            }
        }
        for (; k < end; ++k) {
            int s = csrc[k];
            float w = __expf(lrelu(es[s] + edv));
            l += w;
            acc += w * __half2float(h[(size_t)s * D + c]);
        }
        float v = acc / (l + 1e-16f) + bias[c];
        // LayerNorm within the 32-lane half
        float sm = v, ss = v * v;
        for (int off = 16; off; off >>= 1) {
            sm += __shfl_xor(sm, off);
            ss += __shfl_xor(ss, off);
        }
        float mean = sm / D;
        float var = ss / D - mean * mean;
        float rstd = rsqrtf(var + 1e-5f);
        float o = (v - mean) * rstd * gam[c] + bet[c];
        o = o > 0.f ? o : expm1f(o);
        int g = batch[d];
        int goff = g - g0;
        if (goff >= 0 && goff < 2) {
            atomicAdd(&lsum[goff][c], o);
            atomicMax(&lmax[goff][c], encf(o));
            if (c == 0) atomicAdd(&lcnt[goff], 1.0f);
        } else {
            atomicAdd(&psum[g * D + c], o);
            atomicMax(&pmax[g * D + c], encf(o));
            if (c == 0) atomicAdd(&cnt[g], 1.0f);
        }
    }
    __syncthreads();
    if (tid < 64) {
        int go = tid >> 5, cc = tid & 31;
        unsigned m = lmax[go][cc];
        if (m != 0u) {  // slot touched (all real encodings are nonzero)
            int gg = g0 + go;
            atomicAdd(&psum[gg * D + cc], lsum[go][cc]);
            atomicMax(&pmax[gg * D + cc], m);
            if (cc == 0) atomicAdd(&cnt[gg], lcnt[go]);
        }
    }
}

// ---------- fallback aggregation (online softmax, generic shapes) -----------
__global__ __launch_bounds__(256) void aggr_csr_kernel(
    const int* __restrict__ rowptr, const int* __restrict__ csrc,
    const float* __restrict__ h, const float* __restrict__ es,
    const float* __restrict__ ed, float* __restrict__ outp, int N, int H,
    int C) {
    int D = H * C;
    int wave = (blockIdx.x * blockDim.x + threadIdx.x) >> 6;
    int lane = threadIdx.x & 63;
    if (wave >= N) return;
    int d = wave;
    int c0 = lane, c1 = lane + 64;
    bool a0 = c0 < D, a1 = c1 < D;
    int h0 = a0 ? c0 / C : 0;
    int h1 = a1 ? c1 / C : 0;
    float edv0 = a0 ? ed[d * H + h0] : 0.f;
    float edv1 = a1 ? ed[d * H + h1] : 0.f;
    float m0 = -INFINITY, m1 = -INFINITY;
    float l0 = 0.f, l1 = 0.f, acc0 = 0.f, acc1 = 0.f;
    int beg = rowptr[d], end = rowptr[d + 1];
    for (int k = beg; k < end; ++k) {
        int s = csrc[k];
        const float* hp = h + (size_t)s * D;
        if (a0) {
            float v = lrelu(es[s * H + h0] + edv0);
            float nm = fmaxf(m0, v);
            float sc = __expf(m0 - nm);
            float w = __expf(v - nm);
            l0 = l0 * sc + w;
            acc0 = acc0 * sc + w * hp[c0];
            m0 = nm;
        }
        if (a1) {
            float v = lrelu(es[s * H + h1] + edv1);
            float nm = fmaxf(m1, v);
            float sc = __expf(m1 - nm);
            float w = __expf(v - nm);
            l1 = l1 * sc + w;
            acc1 = acc1 * sc + w * hp[c1];
            m1 = nm;
        }
    }
    if (a0) outp[(size_t)d * D + c0] = acc0 / (l0 + 1e-16f);
    if (a1) outp[(size_t)d * D + c1] = acc1 / (l1 + 1e-16f);
}

// ---------- bias + LayerNorm + ELU (fallback path) --------------------------
__global__ __launch_bounds__(64) void ln_elu_kernel(
    const float* __restrict__ in, const float* __restrict__ bias,
    const float* __restrict__ gam, const float* __restrict__ bet,
    float* __restrict__ outp, int D) {
    int n = blockIdx.x;
    int lane = threadIdx.x;  // blockDim = 64
    int c0 = lane, c1 = lane + 64;
    bool a0 = c0 < D, a1 = c1 < D;
    float v0 = 0.f, v1 = 0.f;
    if (a0) v0 = in[(size_t)n * D + c0] + bias[c0];
    if (a1) v1 = in[(size_t)n * D + c1] + bias[c1];
    float s = v0 + v1;
    float ss = v0 * v0 + v1 * v1;
    for (int off = 32; off; off >>= 1) {
        s += __shfl_xor(s, off);
        ss += __shfl_xor(ss, off);
    }
    float mean = s / D;
    float var = ss / D - mean * mean;
    float rstd = rsqrtf(var + 1e-5f);
    if (a0) {
        float o = (v0 - mean) * rstd * gam[c0] + bet[c0];
        outp[(size_t)n * D + c0] = o > 0.f ? o : expm1f(o);
    }
    if (a1) {
        float o = (v1 - mean) * rstd * gam[c1] + bet[c1];
        outp[(size_t)n * D + c1] = o > 0.f ? o : expm1f(o);
    }
}

// ---------- graph pooling (fallback path) -----------------------------------
__global__ __launch_bounds__(256) void pool_kernel(
    const float* __restrict__ h, const int* __restrict__ batch, int N, int C,
    float* __restrict__ psum, unsigned* __restrict__ pmax,
    float* __restrict__ cnt) {
    int idx = blockIdx.x * blockDim.x + threadIdx.x;
    if (idx >= N * C) return;
    int n = idx / C;
    int c = idx - n * C;
    int g = batch[n];
    float v = h[(size_t)n * C + c];
    atomicAdd(&psum[g * C + c], v);
    atomicMax(&pmax[g * C + c], encf(v));
    if (c == 0) atomicAdd(&cnt[g], 1.0f);
}

// ---------- classifier MLP: one block (1 wave) per graph --------------------
__global__ __launch_bounds__(64) void mlp_kernel(
    const float* __restrict__ psum, const unsigned* __restrict__ pmax,
    const float* __restrict__ cnt, const float* __restrict__ cW1,
    const float* __restrict__ cb1, const float* __restrict__ cW2,
    const float* __restrict__ cb2, const float* __restrict__ cW3,
    const float* __restrict__ cb3, float* __restrict__ outp, int C) {
    __shared__ float f[64];
    __shared__ float t1[32];
    __shared__ float t2[16];
    int g = blockIdx.x;
    int t = threadIdx.x;
    float c = fmaxf(cnt[g], 1.0f);
    if (t < C) {
        f[t] = psum[g * C + t] / c;
    } else if (t < 2 * C) {
        unsigned k = pmax[g * C + (t - C)];
        f[t] = (k == 0u) ? -INFINITY : decf(k);
    }
    __syncthreads();
    if (t < 32) {
        float a = cb1[t];
        for (int i = 0; i < 64; ++i) a += f[i] * cW1[t * 64 + i];
        t1[t] = fmaxf(a, 0.f);
    }
    __syncthreads();
    if (t < 16) {
        float a = cb2[t];
        for (int i = 0; i < 32; ++i) a += t1[i] * cW2[t * 32 + i];
        t2[t] = fmaxf(a, 0.f);
    }
    __syncthreads();
    if (t == 0) {
        float a = cb3[0];
        for (int i = 0; i < 16; ++i) a += t2[i] * cW3[i];
        outp[g] = a;
    }
}

// ---------------------------------------------------------------------------
extern "C" void kernel_launch(void* const* d_in, const int* in_sizes, int n_in,
                              void* d_out, int out_size, void* d_ws,
                              size_t ws_size, hipStream_t stream) {
    const float* x = (const float*)d_in[0];
    const int* ei = (const int*)d_in[1];
    const int* batch = (const int*)d_in[2];
    const float* W1 = (const float*)d_in[4];
    const float* as1 = (const float*)d_in[5];
    const float* ad1 = (const float*)d_in[6];
    const float* b1 = (const float*)d_in[7];
    const float* g1 = (const float*)d_in[8];
    const float* be1 = (const float*)d_in[9];
    const float* W2 = (const float*)d_in[10];
    const float* as2 = (const float*)d_in[11];
    const float* ad2 = (const float*)d_in[12];
    const float* b2 = (const float*)d_in[13];
    const float* g2 = (const float*)d_in[14];
    const float* be2 = (const float*)d_in[15];
    const float* W3 = (const float*)d_in[16];
    const float* as3 = (const float*)d_in[17];
    const float* ad3 = (const float*)d_in[18];
    const float* b3 = (const float*)d_in[19];
    const float* g3 = (const float*)d_in[20];
    const float* be3 = (const float*)d_in[21];
    const float* cW1 = (const float*)d_in[22];
    const float* cb1 = (const float*)d_in[23];
    const float* cW2 = (const float*)d_in[24];
    const float* cb2 = (const float*)d_in[25];
    const float* cW3 = (const float*)d_in[26];
    const float* cb3 = (const float*)d_in[27];

    const int N = in_sizes[2];            // 50000
    const int E = in_sizes[1] / 2;        // 800000
    const int F0 = in_sizes[0] / N;       // 32
    const int Hd = in_sizes[19];          // 32 (b3)
    const int H = in_sizes[5] / Hd;       // 4
    const int D = H * Hd;                 // 128
    const int H3 = in_sizes[17] / Hd;     // 1
    const int G = out_size;               // 512
    const int EN = E + N;
    const bool shapes_ok = (F0 == 32 && Hd == 32 && H == 4 && D == 128 && H3 == 1);

    // -------- workspace carve-out (256B aligned) --------
    char* w = (char*)d_ws;
    size_t off = 0;
    auto carve = [&](size_t bytes) -> void* {
        void* p = w + off;
        off = (off + bytes + 255) & ~(size_t)255;
        return p;
    };
    float* Q = (float*)carve((size_t)N * D * 4);      // fallback fp32 staging
    __half* Qh = (__half*)Q;                          // main path fp16 staging
    float* R = (float*)carve((size_t)N * D * 4);      // fallback scratch
    float* P = (float*)carve((size_t)N * D * 4);      // activations
    float* es = (float*)carve((size_t)N * H * 4);
    float* ed = (float*)carve((size_t)N * H * 4);
    int* rowptr = (int*)carve((size_t)(N + 1) * 4);
    int* cursor = (int*)carve((size_t)N * 4);
    int* csrc = (int*)carve((size_t)EN * 4);
    int* bsum = (int*)carve((size_t)CDIV(N, SCAN_BS) * 4);
    float* psum = (float*)carve((size_t)G * Hd * 4);
    unsigned* pmax = (unsigned*)carve((size_t)G * Hd * 4);
    float* cnt = (float*)carve((size_t)G * 4);
    (void)ws_size;
    (void)n_in;

    const int BLK = 256;
    const int nb = CDIV(N, SCAN_BS);

    // ---------------- CSR build (once, reused by all 3 layers) -------------
    hipMemsetAsync(cursor, 0, (size_t)N * 4, stream);  // use cursor as deg
    deg_kernel<<<CDIV(EN, BLK), BLK, 0, stream>>>(ei, E, N, cursor);
    scan1_kernel<<<nb, SCAN_BS, 0, stream>>>(cursor, rowptr, bsum, N);
    scan2_kernel<<<1, 64, 0, stream>>>(bsum, nb);
    scan3_kernel<<<nb, SCAN_BS, 0, stream>>>(rowptr, cursor, bsum, N, EN);
    scatter_kernel<<<CDIV(EN, BLK), BLK, 0, stream>>>(ei, E, N, cursor, csrc);

    // pooling buffers (used at the end; clear early so it overlaps)
    hipMemsetAsync(psum, 0, (size_t)G * Hd * 4, stream);
    hipMemsetAsync(pmax, 0, (size_t)G * Hd * 4, stream);
    hipMemsetAsync(cnt, 0, (size_t)G * 4, stream);

    if (shapes_ok) {
        // layer 1
        gemm_attn<32, 128, 8, 4, __half><<<CDIV(N, 64), 256, 0, stream>>>(
            x, W1, as1, ad1, Qh, es, ed, N);
        aggr_ln128_kernel<<<CDIV(N, 8), 256, 0, stream>>>(
            rowptr, csrc, Qh, es, ed, b1, g1, be1, P, N);
        // layer 2
        gemm_attn<128, 128, 8, 4, __half><<<CDIV(N, 64), 256, 0, stream>>>(
            P, W2, as2, ad2, Qh, es, ed, N);
        aggr_ln128_kernel<<<CDIV(N, 8), 256, 0, stream>>>(
            rowptr, csrc, Qh, es, ed, b2, g2, be2, P, N);
        // layer 3 (+ fused pooling with block-level LDS reduction)
        gemm_attn<128, 32, 4, 1, __half><<<CDIV(N, 128), 256, 0, stream>>>(
            P, W3, as3, ad3, Qh, es, ed, N);
        aggr_ln32_pool_kernel<<<CDIV(N, 8), 256, 0, stream>>>(
            rowptr, csrc, Qh, es, ed, b3, g3, be3, batch, psum, pmax, cnt, N);
    } else {
        // generic fallback path (all fp32)
        gemm_kernel<<<CDIV(N * D, BLK), BLK, 0, stream>>>(x, W1, Q, N, F0, D);
        attn_kernel<<<CDIV(N * H, BLK), BLK, 0, stream>>>(Q, as1, ad1, es, ed, N, H, Hd);
        aggr_csr_kernel<<<CDIV(N, 4), BLK, 0, stream>>>(rowptr, csrc, Q, es, ed, R, N, H, Hd);
        ln_elu_kernel<<<N, 64, 0, stream>>>(R, b1, g1, be1, P, D);
        gemm_kernel<<<CDIV(N * D, BLK), BLK, 0, stream>>>(P, W2, Q, N, D, D);
        attn_kernel<<<CDIV(N * H, BLK), BLK, 0, stream>>>(Q, as2, ad2, es, ed, N, H, Hd);
        aggr_csr_kernel<<<CDIV(N, 4), BLK, 0, stream>>>(rowptr, csrc, Q, es, ed, R, N, H, Hd);
        ln_elu_kernel<<<N, 64, 0, stream>>>(R, b2, g2, be2, P, D);
        gemm_kernel<<<CDIV(N * Hd, BLK), BLK, 0, stream>>>(P, W3, Q, N, D, Hd);
        attn_kernel<<<CDIV(N * H3, BLK), BLK, 0, stream>>>(Q, as3, ad3, es, ed, N, H3, Hd);
        aggr_csr_kernel<<<CDIV(N, 4), BLK, 0, stream>>>(rowptr, csrc, Q, es, ed, R, N, H3, Hd);
        ln_elu_kernel<<<N, 64, 0, stream>>>(R, b3, g3, be3, P, Hd);
        pool_kernel<<<CDIV(N * Hd, BLK), BLK, 0, stream>>>(P, batch, N, Hd, psum, pmax, cnt);
    }

    mlp_kernel<<<G, 64, 0, stream>>>(psum, pmax, cnt, cW1, cb1, cW2, cb2, cW3,
                                     cb3, (float*)d_out, Hd);
}